// Round 6
// baseline (243.402 us; speedup 1.0000x reference)
//
#include <hip/hip_runtime.h>
#include <hip/hip_bf16.h>

#define D_IN   2048
#define D_ST   16
#define DT_RK  64
#define BB     2
#define LL     2048
#define NCHUNK 64
#define LC     (LL / NCHUNK)   // 32
#define LOG2E  1.4426950408889634f
#define LN2    0.6931471805599453f

// ---------------------------------------------------------------------------
// Kernel 1: x_dbl[bl][k] = sum_d u[bl][d] * W_x[k][d]   (M=4096, N=96, K=2048)
// Split-K (8 ways) -> per-split partial buffers (NO atomics), then reduce.
// ---------------------------------------------------------------------------
#define G1_MT 32
#define G1_KSPLIT 8
#define G1_KPER (D_IN / G1_KSPLIT)  // 256
#define G1_KC 64

__global__ __launch_bounds__(256) void gemm_xdbl(const float* __restrict__ u,
                                                 const float* __restrict__ Wx,
                                                 float* __restrict__ part) {
    __shared__ float us[G1_MT][G1_KC + 4];
    __shared__ float wxs[96][G1_KC + 4];
    const int mt  = blockIdx.x >> 3;         // 128 row tiles
    const int ks  = blockIdx.x & 7;
    const int row0 = mt * G1_MT;
    const int kb0  = ks * G1_KPER;
    const int tid = threadIdx.x;
    const int r0 = tid & 15;                 // rows r0 and r0+16
    const int c0 = (tid >> 4) * 6;           // 6 cols

    float acc[2][6];
#pragma unroll
    for (int i = 0; i < 2; i++)
#pragma unroll
        for (int j = 0; j < 6; j++) acc[i][j] = 0.f;

    for (int kc = 0; kc < G1_KPER; kc += G1_KC) {
        const int kb = kb0 + kc;
#pragma unroll
        for (int i = 0; i < 2; i++) {
            int f4 = tid + i * 256;
            int r = f4 >> 4, k4 = (f4 & 15) * 4;
            *(float4*)&us[r][k4] =
                *(const float4*)&u[(size_t)(row0 + r) * D_IN + kb + k4];
        }
#pragma unroll
        for (int i = 0; i < 6; i++) {
            int f4 = tid + i * 256;
            int c = f4 >> 4, k4 = (f4 & 15) * 4;
            *(float4*)&wxs[c][k4] =
                *(const float4*)&Wx[(size_t)c * D_IN + kb + k4];
        }
        __syncthreads();
#pragma unroll 4
        for (int k4 = 0; k4 < G1_KC; k4 += 4) {
            float4 av[2], bv[6];
            av[0] = *(const float4*)&us[r0][k4];
            av[1] = *(const float4*)&us[r0 + 16][k4];
#pragma unroll
            for (int j = 0; j < 6; j++) bv[j] = *(const float4*)&wxs[c0 + j][k4];
#pragma unroll
            for (int i = 0; i < 2; i++)
#pragma unroll
                for (int j = 0; j < 6; j++) {
                    acc[i][j] = fmaf(av[i].x, bv[j].x, acc[i][j]);
                    acc[i][j] = fmaf(av[i].y, bv[j].y, acc[i][j]);
                    acc[i][j] = fmaf(av[i].z, bv[j].z, acc[i][j]);
                    acc[i][j] = fmaf(av[i].w, bv[j].w, acc[i][j]);
                }
        }
        __syncthreads();
    }
    float* pp = part + (size_t)ks * (BB * LL * 96);
#pragma unroll
    for (int i = 0; i < 2; i++)
#pragma unroll
        for (int j = 0; j < 6; j++)
            pp[(size_t)(row0 + r0 + 16 * i) * 96 + c0 + j] = acc[i][j];
}

// Reduce the 8 split-K partials into xdbl. 393216 floats = 98304 float4.
__global__ __launch_bounds__(256) void reduce_xdbl(const float* __restrict__ part,
                                                   float* __restrict__ xdbl) {
    const size_t i4 = ((size_t)blockIdx.x * 256 + threadIdx.x) * 4;
    const size_t stride = (size_t)BB * LL * 96;
    float4 s = *(const float4*)&part[i4];
#pragma unroll
    for (int k = 1; k < G1_KSPLIT; k++) {
        float4 v = *(const float4*)&part[k * stride + i4];
        s.x += v.x; s.y += v.y; s.z += v.z; s.w += v.w;
    }
    *(float4*)&xdbl[i4] = s;
}

// ---------------------------------------------------------------------------
// Kernel 2: dt[bl][d] = softplus( sum_r xdbl[bl][r] * W_dt[d][r] + b_dt[d] )
// M=4096, N=2048, K=64.  No LDS. Thread owns col d; 32 rows per block with 32
// INDEPENDENT accumulators (ILP=32). Outer loop over k: one w[k] float4 live
// at a time (vector load, coalesced); x reads are wave-uniform -> s_load,
// free on the VALU pipe and shared across the block via the scalar cache.
// ---------------------------------------------------------------------------
#define G2_RPB 32   // rows per block

__global__ __launch_bounds__(256, 4) void gemm_dt(const float* __restrict__ xdbl,
                                                  const float* __restrict__ Wdt,
                                                  const float* __restrict__ bdt,
                                                  float* __restrict__ dt) {
    const int rt = blockIdx.x >> 3;          // 128 row groups
    const int ct = blockIdx.x & 7;           // 8 col groups
    const int row0 = rt * G2_RPB;
    const int d    = ct * 256 + threadIdx.x;

    const float4* wp = (const float4*)&Wdt[(size_t)d * DT_RK];
    const float4* xr = (const float4*)&xdbl[(size_t)row0 * 96];  // row r: xr[r*24 + k]

    float acc[G2_RPB];
#pragma unroll
    for (int r = 0; r < G2_RPB; r++) acc[r] = 0.f;

#pragma unroll 4
    for (int k = 0; k < 16; k++) {
        const float4 w = wp[k];
#pragma unroll
        for (int r = 0; r < G2_RPB; r++) {
            const float4 x = xr[r * 24 + k];   // uniform -> scalar load
            acc[r] = fmaf(x.x, w.x, acc[r]);
            acc[r] = fmaf(x.y, w.y, acc[r]);
            acc[r] = fmaf(x.z, w.z, acc[r]);
            acc[r] = fmaf(x.w, w.w, acc[r]);
        }
    }
    const float bj = bdt[d];
#pragma unroll
    for (int r = 0; r < G2_RPB; r++) {
        float xv = acc[r] + bj;
        // softplus via hw exp2/log2: ln(1+e^x) = max(x,0) + ln(1+e^-|x|)
        float t = __builtin_amdgcn_exp2f(-fabsf(xv) * LOG2E);
        float sp = fmaxf(xv, 0.f) + LN2 * __log2f(1.f + t);
        dt[(size_t)(row0 + r) * D_IN + d] = sp;   // coalesced across lanes
    }
}

// ---------------------------------------------------------------------------
// Scan pass 1: per (b, chunk, d): local scan from h=0 over LC steps.
// B rows read straight from global: wave-uniform address -> scalar loads.
// ---------------------------------------------------------------------------
__global__ __launch_bounds__(256) void scan_pass1(const float* __restrict__ u,
                                                  const float* __restrict__ dt,
                                                  const float* __restrict__ xdbl,
                                                  const float* __restrict__ Alog,
                                                  float* __restrict__ Ssum,
                                                  float* __restrict__ q) {
    const int blk = blockIdx.x;
    const int b  = blk >> 9;
    const int c  = (blk >> 3) & 63;
    const int db = blk & 7;
    const int tid = threadIdx.x;
    const int d = db * 256 + tid;
    const int t0 = c * LC;

    float A2[16];
#pragma unroll
    for (int n4 = 0; n4 < 4; n4++) {
        float4 a = *(const float4*)&Alog[(size_t)d * 16 + n4 * 4];
        A2[n4 * 4 + 0] = -expf(a.x) * LOG2E;
        A2[n4 * 4 + 1] = -expf(a.y) * LOG2E;
        A2[n4 * 4 + 2] = -expf(a.z) * LOG2E;
        A2[n4 * 4 + 3] = -expf(a.w) * LOG2E;
    }

    float h[16];
#pragma unroll
    for (int n = 0; n < 16; n++) h[n] = 0.f;
    float S = 0.f;

    const float* bcrow = &xdbl[(size_t)(b * LL + t0) * 96];   // uniform
    const float* dtp = &dt[(size_t)(b * LL + t0) * D_IN + d];
    const float* up  = &u [(size_t)(b * LL + t0) * D_IN + d];
    float dt_nxt = dtp[0], u_nxt = up[0];
    for (int t = 0; t < LC; t++) {
        float dv = dt_nxt, uv = u_nxt;
        if (t + 1 < LC) { dt_nxt = dtp[(size_t)(t + 1) * D_IN]; u_nxt = up[(size_t)(t + 1) * D_IN]; }
        S += dv;
        float dtu = dv * uv;
        float4 b0 = *(const float4*)&bcrow[t * 96 + 64];
        float4 b1 = *(const float4*)&bcrow[t * 96 + 68];
        float4 b2 = *(const float4*)&bcrow[t * 96 + 72];
        float4 b3 = *(const float4*)&bcrow[t * 96 + 76];
        const float Bt[16] = {b0.x,b0.y,b0.z,b0.w, b1.x,b1.y,b1.z,b1.w,
                              b2.x,b2.y,b2.z,b2.w, b3.x,b3.y,b3.z,b3.w};
#pragma unroll
        for (int n = 0; n < 16; n++) {
            float a = __builtin_amdgcn_exp2f(dv * A2[n]);
            h[n] = fmaf(a, h[n], dtu * Bt[n]);
        }
    }
    Ssum[(size_t)(b * NCHUNK + c) * D_IN + d] = S;
#pragma unroll
    for (int n = 0; n < 16; n++)
        q[((size_t)((b * NCHUNK + c) * 16 + n)) * D_IN + d] = h[n];
}

// ---------------------------------------------------------------------------
// Combine: per (b,n,d): sequentially fold chunks IN-PLACE.
// On exit q[b][c][n][d] holds h_init for chunk c.
// ---------------------------------------------------------------------------
__global__ __launch_bounds__(256) void scan_combine(const float* __restrict__ Alog,
                                                    const float* __restrict__ Ssum,
                                                    float* __restrict__ q) {
    const int gid = blockIdx.x * 256 + threadIdx.x;  // B*16*2048 = 65536
    const int d = gid & 2047;
    const int n = (gid >> 11) & 15;
    const int b = gid >> 15;
    const float A2 = -expf(Alog[(size_t)d * 16 + n]) * LOG2E;
    float h = 0.f;
    for (int c = 0; c < NCHUNK; c++) {
        size_t idx = ((size_t)((b * NCHUNK + c) * 16 + n)) * D_IN + d;
        float qv = q[idx];
        float S  = Ssum[(size_t)(b * NCHUNK + c) * D_IN + d];
        q[idx] = h;   // h_init for chunk c
        h = fmaf(__builtin_amdgcn_exp2f(A2 * S), h, qv);
    }
}

// ---------------------------------------------------------------------------
// Scan pass 2: re-scan each chunk from h_init, emit y = sum_n h*C + u*D (fp32)
// ---------------------------------------------------------------------------
__global__ __launch_bounds__(256) void scan_pass2(const float* __restrict__ u,
                                                  const float* __restrict__ dt,
                                                  const float* __restrict__ xdbl,
                                                  const float* __restrict__ Alog,
                                                  const float* __restrict__ Dv,
                                                  const float* __restrict__ hinit,
                                                  float* __restrict__ out) {
    const int blk = blockIdx.x;
    const int b  = blk >> 9;
    const int c  = (blk >> 3) & 63;
    const int db = blk & 7;
    const int tid = threadIdx.x;
    const int d = db * 256 + tid;
    const int t0 = c * LC;

    float A2[16];
#pragma unroll
    for (int n4 = 0; n4 < 4; n4++) {
        float4 a = *(const float4*)&Alog[(size_t)d * 16 + n4 * 4];
        A2[n4 * 4 + 0] = -expf(a.x) * LOG2E;
        A2[n4 * 4 + 1] = -expf(a.y) * LOG2E;
        A2[n4 * 4 + 2] = -expf(a.z) * LOG2E;
        A2[n4 * 4 + 3] = -expf(a.w) * LOG2E;
    }
    const float Dd = Dv[d];
    float h[16];
#pragma unroll
    for (int n = 0; n < 16; n++)
        h[n] = hinit[((size_t)((b * NCHUNK + c) * 16 + n)) * D_IN + d];

    const float* bcrow = &xdbl[(size_t)(b * LL + t0) * 96];   // uniform
    const float* dtp = &dt[(size_t)(b * LL + t0) * D_IN + d];
    const float* up  = &u [(size_t)(b * LL + t0) * D_IN + d];
    float* op = &out[(size_t)(b * LL + t0) * D_IN + d];
    float dt_nxt = dtp[0], u_nxt = up[0];
    for (int t = 0; t < LC; t++) {
        float dv = dt_nxt, uv = u_nxt;
        if (t + 1 < LC) { dt_nxt = dtp[(size_t)(t + 1) * D_IN]; u_nxt = up[(size_t)(t + 1) * D_IN]; }
        float dtu = dv * uv;
        float4 b0 = *(const float4*)&bcrow[t * 96 + 64];
        float4 b1 = *(const float4*)&bcrow[t * 96 + 68];
        float4 b2 = *(const float4*)&bcrow[t * 96 + 72];
        float4 b3 = *(const float4*)&bcrow[t * 96 + 76];
        float4 c0v = *(const float4*)&bcrow[t * 96 + 80];
        float4 c1v = *(const float4*)&bcrow[t * 96 + 84];
        float4 c2v = *(const float4*)&bcrow[t * 96 + 88];
        float4 c3v = *(const float4*)&bcrow[t * 96 + 92];
        const float Bt[16] = {b0.x,b0.y,b0.z,b0.w, b1.x,b1.y,b1.z,b1.w,
                              b2.x,b2.y,b2.z,b2.w, b3.x,b3.y,b3.z,b3.w};
        const float Ct[16] = {c0v.x,c0v.y,c0v.z,c0v.w, c1v.x,c1v.y,c1v.z,c1v.w,
                              c2v.x,c2v.y,c2v.z,c2v.w, c3v.x,c3v.y,c3v.z,c3v.w};
        float y = 0.f;
#pragma unroll
        for (int n = 0; n < 16; n++) {
            float a = __builtin_amdgcn_exp2f(dv * A2[n]);
            h[n] = fmaf(a, h[n], dtu * Bt[n]);
            y = fmaf(h[n], Ct[n], y);
        }
        op[(size_t)t * D_IN] = fmaf(uv, Dd, y);
    }
}

// ---------------------------------------------------------------------------
extern "C" void kernel_launch(void* const* d_in, const int* in_sizes, int n_in,
                              void* d_out, int out_size, void* d_ws, size_t ws_size,
                              hipStream_t stream) {
    const float* u    = (const float*)d_in[0];
    const float* Alog = (const float*)d_in[1];
    const float* Dv   = (const float*)d_in[2];
    const float* Wx   = (const float*)d_in[3];
    const float* Wdt  = (const float*)d_in[4];
    const float* bdt  = (const float*)d_in[5];
    float* out = (float*)d_out;

    float* ws   = (float*)d_ws;
    float* xdbl = ws;                                   // B*L*96     =   393216 f
    float* dtb  = xdbl + (size_t)BB * LL * 96;          // B*L*2048   =  8388608 f
    float* Ssum = dtb + (size_t)BB * LL * D_IN;         // B*C*2048   =   262144 f
    float* q    = Ssum + (size_t)BB * NCHUNK * D_IN;    // B*C*16*2048 = 4194304 f
    float* part = Ssum;  // split-K partials alias Ssum+q (dead after reduce)
    // total: 13,238,272 floats = 52.9 MB

    gemm_xdbl <<<128 * G1_KSPLIT, 256, 0, stream>>>(u, Wx, part);
    reduce_xdbl<<<384,            256, 0, stream>>>(part, xdbl);
    gemm_dt   <<<128 * 8,         256, 0, stream>>>(xdbl, Wdt, bdt, dtb);
    scan_pass1<<<BB * NCHUNK * 8, 256, 0, stream>>>(u, dtb, xdbl, Alog, Ssum, q);
    scan_combine<<<BB * 16 * D_IN / 256, 256, 0, stream>>>(Alog, Ssum, q);
    scan_pass2<<<BB * NCHUNK * 8, 256, 0, stream>>>(u, dtb, xdbl, Alog, Dv, q, out);
}

// Round 7
// 206.030 us; speedup vs baseline: 1.1814x; 1.1814x over previous
//
#include <hip/hip_runtime.h>
#include <hip/hip_bf16.h>

#define D_IN   2048
#define D_ST   16
#define DT_RK  64
#define BB     2
#define LL     2048
#define NCHUNK 64
#define LC     (LL / NCHUNK)   // 32
#define LOG2E  1.4426950408889634f
#define LN2    0.6931471805599453f

// ---------------------------------------------------------------------------
// Kernel 1: x_dbl[bl][k] = sum_d u[bl][d] * W_x[k][d]   (M=4096, N=96, K=2048)
// Split-K (8 ways) -> per-split partial buffers (NO atomics), then reduce.
// ---------------------------------------------------------------------------
#define G1_MT 32
#define G1_KSPLIT 8
#define G1_KPER (D_IN / G1_KSPLIT)  // 256
#define G1_KC 64

__global__ __launch_bounds__(256) void gemm_xdbl(const float* __restrict__ u,
                                                 const float* __restrict__ Wx,
                                                 float* __restrict__ part) {
    __shared__ float us[G1_MT][G1_KC + 4];
    __shared__ float wxs[96][G1_KC + 4];
    const int mt  = blockIdx.x >> 3;         // 128 row tiles
    const int ks  = blockIdx.x & 7;
    const int row0 = mt * G1_MT;
    const int kb0  = ks * G1_KPER;
    const int tid = threadIdx.x;
    const int r0 = tid & 15;                 // rows r0 and r0+16
    const int c0 = (tid >> 4) * 6;           // 6 cols

    float acc[2][6];
#pragma unroll
    for (int i = 0; i < 2; i++)
#pragma unroll
        for (int j = 0; j < 6; j++) acc[i][j] = 0.f;

    for (int kc = 0; kc < G1_KPER; kc += G1_KC) {
        const int kb = kb0 + kc;
#pragma unroll
        for (int i = 0; i < 2; i++) {
            int f4 = tid + i * 256;
            int r = f4 >> 4, k4 = (f4 & 15) * 4;
            *(float4*)&us[r][k4] =
                *(const float4*)&u[(size_t)(row0 + r) * D_IN + kb + k4];
        }
#pragma unroll
        for (int i = 0; i < 6; i++) {
            int f4 = tid + i * 256;
            int c = f4 >> 4, k4 = (f4 & 15) * 4;
            *(float4*)&wxs[c][k4] =
                *(const float4*)&Wx[(size_t)c * D_IN + kb + k4];
        }
        __syncthreads();
#pragma unroll 4
        for (int k4 = 0; k4 < G1_KC; k4 += 4) {
            float4 av[2], bv[6];
            av[0] = *(const float4*)&us[r0][k4];
            av[1] = *(const float4*)&us[r0 + 16][k4];
#pragma unroll
            for (int j = 0; j < 6; j++) bv[j] = *(const float4*)&wxs[c0 + j][k4];
#pragma unroll
            for (int i = 0; i < 2; i++)
#pragma unroll
                for (int j = 0; j < 6; j++) {
                    acc[i][j] = fmaf(av[i].x, bv[j].x, acc[i][j]);
                    acc[i][j] = fmaf(av[i].y, bv[j].y, acc[i][j]);
                    acc[i][j] = fmaf(av[i].z, bv[j].z, acc[i][j]);
                    acc[i][j] = fmaf(av[i].w, bv[j].w, acc[i][j]);
                }
        }
        __syncthreads();
    }
    float* pp = part + (size_t)ks * (BB * LL * 96);
#pragma unroll
    for (int i = 0; i < 2; i++)
#pragma unroll
        for (int j = 0; j < 6; j++)
            pp[(size_t)(row0 + r0 + 16 * i) * 96 + c0 + j] = acc[i][j];
}

// Reduce the 8 split-K partials into xdbl. 393216 floats = 98304 float4.
__global__ __launch_bounds__(256) void reduce_xdbl(const float* __restrict__ part,
                                                   float* __restrict__ xdbl) {
    const size_t i4 = ((size_t)blockIdx.x * 256 + threadIdx.x) * 4;
    const size_t stride = (size_t)BB * LL * 96;
    float4 s = *(const float4*)&part[i4];
#pragma unroll
    for (int k = 1; k < G1_KSPLIT; k++) {
        float4 v = *(const float4*)&part[k * stride + i4];
        s.x += v.x; s.y += v.y; s.z += v.z; s.w += v.w;
    }
    *(float4*)&xdbl[i4] = s;
}

// ---------------------------------------------------------------------------
// Kernel 2: dt[bl][d] = softplus( sum_r xdbl[bl][r] * W_dt[d][r] + b_dt[d] )
// M=4096, N=2048, K=64.  Canonical tiled fp32 GEMM: 128x128 block tile,
// K=64 one-shot, k-major LDS (As[k][row], Bs[k][col]), 8x8 register tile.
// Hot loop per k: 4x ds_read_b128 + 64 FMA -> FMA-bound.
// ---------------------------------------------------------------------------
#define G2_LDA 132   // 128 + 4: k-row stride (mult of 4 for b128 alignment)

__global__ __launch_bounds__(256, 4) void gemm_dt(const float* __restrict__ xdbl,
                                                  const float* __restrict__ Wdt,
                                                  const float* __restrict__ bdt,
                                                  float* __restrict__ dt) {
    __shared__ float As[DT_RK][G2_LDA];   // [k][row]
    __shared__ float Bs[DT_RK][G2_LDA];   // [k][col]
    const int rt = blockIdx.x >> 4;       // 32 row tiles
    const int ct = blockIdx.x & 15;       // 16 col tiles
    const int row0 = rt * 128, col0 = ct * 128;
    const int tid = threadIdx.x;

    // Stage A: xdbl[row0+row][kg*4+j] -> As[kg*4+j][row]   (2048 f4, 8/thread)
    // Stage B: Wdt [col0+col][kg*4+j] -> Bs[kg*4+j][col]
#pragma unroll
    for (int i = 0; i < 8; i++) {
        int f4 = tid + i * 256;
        int r  = f4 >> 4;           // 0..127
        int kg = f4 & 15;           // 0..15
        float4 a = *(const float4*)&xdbl[(size_t)(row0 + r) * 96 + kg * 4];
        float4 b = *(const float4*)&Wdt[(size_t)(col0 + r) * DT_RK + kg * 4];
        As[kg * 4 + 0][r] = a.x; As[kg * 4 + 1][r] = a.y;
        As[kg * 4 + 2][r] = a.z; As[kg * 4 + 3][r] = a.w;
        Bs[kg * 4 + 0][r] = b.x; Bs[kg * 4 + 1][r] = b.y;
        Bs[kg * 4 + 2][r] = b.z; Bs[kg * 4 + 3][r] = b.w;
    }
    __syncthreads();

    const int ty = tid >> 4;       // 0..15 -> rows ty*8..+8
    const int tx = tid & 15;       // 0..15 -> cols tx*8..+8
    float acc[8][8];
#pragma unroll
    for (int i = 0; i < 8; i++)
#pragma unroll
        for (int j = 0; j < 8; j++) acc[i][j] = 0.f;

#pragma unroll 2
    for (int k = 0; k < DT_RK; k++) {
        float4 a0 = *(const float4*)&As[k][ty * 8];
        float4 a1 = *(const float4*)&As[k][ty * 8 + 4];
        float4 b0 = *(const float4*)&Bs[k][tx * 8];
        float4 b1 = *(const float4*)&Bs[k][tx * 8 + 4];
        const float av[8] = {a0.x,a0.y,a0.z,a0.w, a1.x,a1.y,a1.z,a1.w};
        const float bv[8] = {b0.x,b0.y,b0.z,b0.w, b1.x,b1.y,b1.z,b1.w};
#pragma unroll
        for (int i = 0; i < 8; i++)
#pragma unroll
            for (int j = 0; j < 8; j++)
                acc[i][j] = fmaf(av[i], bv[j], acc[i][j]);
    }

    float4 bj0 = *(const float4*)&bdt[col0 + tx * 8];
    float4 bj1 = *(const float4*)&bdt[col0 + tx * 8 + 4];
    const float bj[8] = {bj0.x,bj0.y,bj0.z,bj0.w, bj1.x,bj1.y,bj1.z,bj1.w};
#pragma unroll
    for (int i = 0; i < 8; i++) {
        float out[8];
#pragma unroll
        for (int j = 0; j < 8; j++) {
            float xv = acc[i][j] + bj[j];
            float t = __builtin_amdgcn_exp2f(-fabsf(xv) * LOG2E);
            out[j] = fmaxf(xv, 0.f) + LN2 * __log2f(1.f + t);
        }
        float* op = &dt[(size_t)(row0 + ty * 8 + i) * D_IN + col0 + tx * 8];
        *(float4*)&op[0] = make_float4(out[0], out[1], out[2], out[3]);
        *(float4*)&op[4] = make_float4(out[4], out[5], out[6], out[7]);
    }
}

// ---------------------------------------------------------------------------
// Scan pass 1: per (b, chunk, d): local scan from h=0 over LC steps.
// B rows read straight from global: wave-uniform address -> scalar loads.
// ---------------------------------------------------------------------------
__global__ __launch_bounds__(256) void scan_pass1(const float* __restrict__ u,
                                                  const float* __restrict__ dt,
                                                  const float* __restrict__ xdbl,
                                                  const float* __restrict__ Alog,
                                                  float* __restrict__ Ssum,
                                                  float* __restrict__ q) {
    const int blk = blockIdx.x;
    const int b  = blk >> 9;
    const int c  = (blk >> 3) & 63;
    const int db = blk & 7;
    const int tid = threadIdx.x;
    const int d = db * 256 + tid;
    const int t0 = c * LC;

    float A2[16];
#pragma unroll
    for (int n4 = 0; n4 < 4; n4++) {
        float4 a = *(const float4*)&Alog[(size_t)d * 16 + n4 * 4];
        A2[n4 * 4 + 0] = -expf(a.x) * LOG2E;
        A2[n4 * 4 + 1] = -expf(a.y) * LOG2E;
        A2[n4 * 4 + 2] = -expf(a.z) * LOG2E;
        A2[n4 * 4 + 3] = -expf(a.w) * LOG2E;
    }

    float h[16];
#pragma unroll
    for (int n = 0; n < 16; n++) h[n] = 0.f;
    float S = 0.f;

    const float* bcrow = &xdbl[(size_t)(b * LL + t0) * 96];   // uniform
    const float* dtp = &dt[(size_t)(b * LL + t0) * D_IN + d];
    const float* up  = &u [(size_t)(b * LL + t0) * D_IN + d];
    float dt_nxt = dtp[0], u_nxt = up[0];
    for (int t = 0; t < LC; t++) {
        float dv = dt_nxt, uv = u_nxt;
        if (t + 1 < LC) { dt_nxt = dtp[(size_t)(t + 1) * D_IN]; u_nxt = up[(size_t)(t + 1) * D_IN]; }
        S += dv;
        float dtu = dv * uv;
        float4 b0 = *(const float4*)&bcrow[t * 96 + 64];
        float4 b1 = *(const float4*)&bcrow[t * 96 + 68];
        float4 b2 = *(const float4*)&bcrow[t * 96 + 72];
        float4 b3 = *(const float4*)&bcrow[t * 96 + 76];
        const float Bt[16] = {b0.x,b0.y,b0.z,b0.w, b1.x,b1.y,b1.z,b1.w,
                              b2.x,b2.y,b2.z,b2.w, b3.x,b3.y,b3.z,b3.w};
#pragma unroll
        for (int n = 0; n < 16; n++) {
            float a = __builtin_amdgcn_exp2f(dv * A2[n]);
            h[n] = fmaf(a, h[n], dtu * Bt[n]);
        }
    }
    Ssum[(size_t)(b * NCHUNK + c) * D_IN + d] = S;
#pragma unroll
    for (int n = 0; n < 16; n++)
        q[((size_t)((b * NCHUNK + c) * 16 + n)) * D_IN + d] = h[n];
}

// ---------------------------------------------------------------------------
// Combine: per (b,n,d): sequentially fold chunks IN-PLACE.
// On exit q[b][c][n][d] holds h_init for chunk c.
// ---------------------------------------------------------------------------
__global__ __launch_bounds__(256) void scan_combine(const float* __restrict__ Alog,
                                                    const float* __restrict__ Ssum,
                                                    float* __restrict__ q) {
    const int gid = blockIdx.x * 256 + threadIdx.x;  // B*16*2048 = 65536
    const int d = gid & 2047;
    const int n = (gid >> 11) & 15;
    const int b = gid >> 15;
    const float A2 = -expf(Alog[(size_t)d * 16 + n]) * LOG2E;
    float h = 0.f;
    for (int c = 0; c < NCHUNK; c++) {
        size_t idx = ((size_t)((b * NCHUNK + c) * 16 + n)) * D_IN + d;
        float qv = q[idx];
        float S  = Ssum[(size_t)(b * NCHUNK + c) * D_IN + d];
        q[idx] = h;   // h_init for chunk c
        h = fmaf(__builtin_amdgcn_exp2f(A2 * S), h, qv);
    }
}

// ---------------------------------------------------------------------------
// Scan pass 2: re-scan each chunk from h_init, emit y = sum_n h*C + u*D (fp32)
// ---------------------------------------------------------------------------
__global__ __launch_bounds__(256) void scan_pass2(const float* __restrict__ u,
                                                  const float* __restrict__ dt,
                                                  const float* __restrict__ xdbl,
                                                  const float* __restrict__ Alog,
                                                  const float* __restrict__ Dv,
                                                  const float* __restrict__ hinit,
                                                  float* __restrict__ out) {
    const int blk = blockIdx.x;
    const int b  = blk >> 9;
    const int c  = (blk >> 3) & 63;
    const int db = blk & 7;
    const int tid = threadIdx.x;
    const int d = db * 256 + tid;
    const int t0 = c * LC;

    float A2[16];
#pragma unroll
    for (int n4 = 0; n4 < 4; n4++) {
        float4 a = *(const float4*)&Alog[(size_t)d * 16 + n4 * 4];
        A2[n4 * 4 + 0] = -expf(a.x) * LOG2E;
        A2[n4 * 4 + 1] = -expf(a.y) * LOG2E;
        A2[n4 * 4 + 2] = -expf(a.z) * LOG2E;
        A2[n4 * 4 + 3] = -expf(a.w) * LOG2E;
    }
    const float Dd = Dv[d];
    float h[16];
#pragma unroll
    for (int n = 0; n < 16; n++)
        h[n] = hinit[((size_t)((b * NCHUNK + c) * 16 + n)) * D_IN + d];

    const float* bcrow = &xdbl[(size_t)(b * LL + t0) * 96];   // uniform
    const float* dtp = &dt[(size_t)(b * LL + t0) * D_IN + d];
    const float* up  = &u [(size_t)(b * LL + t0) * D_IN + d];
    float* op = &out[(size_t)(b * LL + t0) * D_IN + d];
    float dt_nxt = dtp[0], u_nxt = up[0];
    for (int t = 0; t < LC; t++) {
        float dv = dt_nxt, uv = u_nxt;
        if (t + 1 < LC) { dt_nxt = dtp[(size_t)(t + 1) * D_IN]; u_nxt = up[(size_t)(t + 1) * D_IN]; }
        float dtu = dv * uv;
        float4 b0 = *(const float4*)&bcrow[t * 96 + 64];
        float4 b1 = *(const float4*)&bcrow[t * 96 + 68];
        float4 b2 = *(const float4*)&bcrow[t * 96 + 72];
        float4 b3 = *(const float4*)&bcrow[t * 96 + 76];
        float4 c0v = *(const float4*)&bcrow[t * 96 + 80];
        float4 c1v = *(const float4*)&bcrow[t * 96 + 84];
        float4 c2v = *(const float4*)&bcrow[t * 96 + 88];
        float4 c3v = *(const float4*)&bcrow[t * 96 + 92];
        const float Bt[16] = {b0.x,b0.y,b0.z,b0.w, b1.x,b1.y,b1.z,b1.w,
                              b2.x,b2.y,b2.z,b2.w, b3.x,b3.y,b3.z,b3.w};
        const float Ct[16] = {c0v.x,c0v.y,c0v.z,c0v.w, c1v.x,c1v.y,c1v.z,c1v.w,
                              c2v.x,c2v.y,c2v.z,c2v.w, c3v.x,c3v.y,c3v.z,c3v.w};
        float y = 0.f;
#pragma unroll
        for (int n = 0; n < 16; n++) {
            float a = __builtin_amdgcn_exp2f(dv * A2[n]);
            h[n] = fmaf(a, h[n], dtu * Bt[n]);
            y = fmaf(h[n], Ct[n], y);
        }
        op[(size_t)t * D_IN] = fmaf(uv, Dd, y);
    }
}

// ---------------------------------------------------------------------------
extern "C" void kernel_launch(void* const* d_in, const int* in_sizes, int n_in,
                              void* d_out, int out_size, void* d_ws, size_t ws_size,
                              hipStream_t stream) {
    const float* u    = (const float*)d_in[0];
    const float* Alog = (const float*)d_in[1];
    const float* Dv   = (const float*)d_in[2];
    const float* Wx   = (const float*)d_in[3];
    const float* Wdt  = (const float*)d_in[4];
    const float* bdt  = (const float*)d_in[5];
    float* out = (float*)d_out;

    float* ws   = (float*)d_ws;
    float* xdbl = ws;                                   // B*L*96     =   393216 f
    float* dtb  = xdbl + (size_t)BB * LL * 96;          // B*L*2048   =  8388608 f
    float* Ssum = dtb + (size_t)BB * LL * D_IN;         // B*C*2048   =   262144 f
    float* q    = Ssum + (size_t)BB * NCHUNK * D_IN;    // B*C*16*2048 = 4194304 f
    float* part = Ssum;  // split-K partials alias Ssum+q (dead after reduce)
    // total: 13,238,272 floats = 52.9 MB

    gemm_xdbl <<<128 * G1_KSPLIT, 256, 0, stream>>>(u, Wx, part);
    reduce_xdbl<<<384,            256, 0, stream>>>(part, xdbl);
    gemm_dt   <<<32 * 16,         256, 0, stream>>>(xdbl, Wdt, bdt, dtb);
    scan_pass1<<<BB * NCHUNK * 8, 256, 0, stream>>>(u, dtb, xdbl, Alog, Ssum, q);
    scan_combine<<<BB * 16 * D_IN / 256, 256, 0, stream>>>(Alog, Ssum, q);
    scan_pass2<<<BB * NCHUNK * 8, 256, 0, stream>>>(u, dtb, xdbl, Alog, Dv, q, out);
}

// Round 8
// 204.294 us; speedup vs baseline: 1.1914x; 1.0085x over previous
//
#include <hip/hip_runtime.h>
#include <hip/hip_bf16.h>

#define D_IN   2048
#define D_ST   16
#define DT_RK  64
#define BB     2
#define LL     2048
#define NCHUNK 64
#define LC     (LL / NCHUNK)   // 32
#define LOG2E  1.4426950408889634f
#define LN2    0.6931471805599453f

static __device__ __forceinline__ unsigned short f2bf(float v) {
    __hip_bfloat16 h = __float2bfloat16(v);
    return *(unsigned short*)&h;
}

// ---------------------------------------------------------------------------
// Kernel 1: x_dbl[bl][k] = sum_d u[bl][d] * W_x[k][d]   (M=4096, N=96, K=2048)
// 128x96 tile, KSPLIT=16 (K-range 128, BK=64), k-major LDS, 8x6 micro-tile.
// Grid = 32*16 = 512 blocks, 2 blocks/CU (LDS 59 KB).
// ---------------------------------------------------------------------------
#define X1_KSPLIT 16
#define X1_LDA 132
#define X1_LDB 100

__global__ __launch_bounds__(256, 4) void gemm_xdbl(const float* __restrict__ u,
                                                    const float* __restrict__ Wx,
                                                    float* __restrict__ part) {
    __shared__ float As[64][X1_LDA];   // [k][row 0..127]
    __shared__ float Bs[64][X1_LDB];   // [k][col 0..95]
    const int mt = blockIdx.x >> 4;          // 32 row tiles
    const int ks = blockIdx.x & 15;          // 16 k splits
    const int row0 = mt * 128;
    const int kb0  = ks * 128;
    const int tid = threadIdx.x;
    const int ty = tid >> 4;                 // 0..15 -> rows ty*8..+8
    const int tx = tid & 15;                 // 0..15 -> cols tx*6..+6

    float acc[8][6];
#pragma unroll
    for (int i = 0; i < 8; i++)
#pragma unroll
        for (int j = 0; j < 6; j++) acc[i][j] = 0.f;

    for (int kc = 0; kc < 128; kc += 64) {
        const int kb = kb0 + kc;
        // stage A: 128 rows x 64 k = 2048 f4, 8/thread, transposed to k-major
#pragma unroll
        for (int i = 0; i < 8; i++) {
            int f = tid + i * 256;
            int r = f >> 4, kg = f & 15;
            float4 a = *(const float4*)&u[(size_t)(row0 + r) * D_IN + kb + kg * 4];
            As[kg * 4 + 0][r] = a.x; As[kg * 4 + 1][r] = a.y;
            As[kg * 4 + 2][r] = a.z; As[kg * 4 + 3][r] = a.w;
        }
        // stage B: 96 cols x 64 k = 1536 f4, 6/thread
#pragma unroll
        for (int i = 0; i < 6; i++) {
            int f = tid + i * 256;
            int c = f >> 4, kg = f & 15;
            float4 b = *(const float4*)&Wx[(size_t)c * D_IN + kb + kg * 4];
            Bs[kg * 4 + 0][c] = b.x; Bs[kg * 4 + 1][c] = b.y;
            Bs[kg * 4 + 2][c] = b.z; Bs[kg * 4 + 3][c] = b.w;
        }
        __syncthreads();
#pragma unroll 2
        for (int k = 0; k < 64; k++) {
            float4 a0 = *(const float4*)&As[k][ty * 8];
            float4 a1 = *(const float4*)&As[k][ty * 8 + 4];
            float2 b0 = *(const float2*)&Bs[k][tx * 6];
            float2 b1 = *(const float2*)&Bs[k][tx * 6 + 2];
            float2 b2 = *(const float2*)&Bs[k][tx * 6 + 4];
            const float av[8] = {a0.x,a0.y,a0.z,a0.w, a1.x,a1.y,a1.z,a1.w};
            const float bv[6] = {b0.x,b0.y, b1.x,b1.y, b2.x,b2.y};
#pragma unroll
            for (int i = 0; i < 8; i++)
#pragma unroll
                for (int j = 0; j < 6; j++)
                    acc[i][j] = fmaf(av[i], bv[j], acc[i][j]);
        }
        __syncthreads();
    }
    float* pp = part + (size_t)ks * (BB * LL * 96);
#pragma unroll
    for (int i = 0; i < 8; i++) {
        float* op = &pp[(size_t)(row0 + ty * 8 + i) * 96 + tx * 6];
        *(float2*)&op[0] = make_float2(acc[i][0], acc[i][1]);
        *(float2*)&op[2] = make_float2(acc[i][2], acc[i][3]);
        *(float2*)&op[4] = make_float2(acc[i][4], acc[i][5]);
    }
}

// Reduce the 16 split-K partials into xdbl. 393216 floats = 98304 float4.
__global__ __launch_bounds__(256) void reduce_xdbl(const float* __restrict__ part,
                                                   float* __restrict__ xdbl) {
    const size_t i4 = ((size_t)blockIdx.x * 256 + threadIdx.x) * 4;
    const size_t stride = (size_t)BB * LL * 96;
    float4 s = *(const float4*)&part[i4];
#pragma unroll
    for (int k = 1; k < X1_KSPLIT; k++) {
        float4 v = *(const float4*)&part[k * stride + i4];
        s.x += v.x; s.y += v.y; s.z += v.z; s.w += v.w;
    }
    *(float4*)&xdbl[i4] = s;
}

// ---------------------------------------------------------------------------
// Kernel 2: dt[bl][d] = softplus( sum_r xdbl[bl][r] * W_dt[d][r] + b_dt[d] )
// 128x128 tile, K=64 one-shot, k-major LDS, 8x8 register tile with SPLIT
// fragments {x*4, 64+x*4} -> all LDS fragment reads <=2-way (free).
// Output dt in BF16 (halves dt HBM traffic for the scans).
// ---------------------------------------------------------------------------
#define G2_LDA 132

__global__ __launch_bounds__(256, 4) void gemm_dt(const float* __restrict__ xdbl,
                                                  const float* __restrict__ Wdt,
                                                  const float* __restrict__ bdt,
                                                  __hip_bfloat16* __restrict__ dt) {
    __shared__ float As[DT_RK][G2_LDA];   // [k][row]
    __shared__ float Bs[DT_RK][G2_LDA];   // [k][col]
    const int rt = blockIdx.x >> 4;       // 32 row tiles
    const int ct = blockIdx.x & 15;       // 16 col tiles
    const int row0 = rt * 128, col0 = ct * 128;
    const int tid = threadIdx.x;

#pragma unroll
    for (int i = 0; i < 8; i++) {
        int f = tid + i * 256;
        int r  = f >> 4;            // 0..127
        int kg = f & 15;            // 0..15
        float4 a = *(const float4*)&xdbl[(size_t)(row0 + r) * 96 + kg * 4];
        float4 b = *(const float4*)&Wdt[(size_t)(col0 + r) * DT_RK + kg * 4];
        As[kg * 4 + 0][r] = a.x; As[kg * 4 + 1][r] = a.y;
        As[kg * 4 + 2][r] = a.z; As[kg * 4 + 3][r] = a.w;
        Bs[kg * 4 + 0][r] = b.x; Bs[kg * 4 + 1][r] = b.y;
        Bs[kg * 4 + 2][r] = b.z; Bs[kg * 4 + 3][r] = b.w;
    }
    __syncthreads();

    const int ty = tid >> 4;       // rows {ty*4+i, 64+ty*4+i}
    const int tx = tid & 15;       // cols {tx*4+j, 64+tx*4+j}
    float acc[8][8];
#pragma unroll
    for (int i = 0; i < 8; i++)
#pragma unroll
        for (int j = 0; j < 8; j++) acc[i][j] = 0.f;

#pragma unroll 2
    for (int k = 0; k < DT_RK; k++) {
        float4 a0 = *(const float4*)&As[k][ty * 4];
        float4 a1 = *(const float4*)&As[k][ty * 4 + 64];
        float4 b0 = *(const float4*)&Bs[k][tx * 4];
        float4 b1 = *(const float4*)&Bs[k][tx * 4 + 64];
        const float av[8] = {a0.x,a0.y,a0.z,a0.w, a1.x,a1.y,a1.z,a1.w};
        const float bv[8] = {b0.x,b0.y,b0.z,b0.w, b1.x,b1.y,b1.z,b1.w};
#pragma unroll
        for (int i = 0; i < 8; i++)
#pragma unroll
            for (int j = 0; j < 8; j++)
                acc[i][j] = fmaf(av[i], bv[j], acc[i][j]);
    }

    float4 bj0 = *(const float4*)&bdt[col0 + tx * 4];
    float4 bj1 = *(const float4*)&bdt[col0 + 64 + tx * 4];
    const float bj[8] = {bj0.x,bj0.y,bj0.z,bj0.w, bj1.x,bj1.y,bj1.z,bj1.w};
#pragma unroll
    for (int i = 0; i < 8; i++) {
        const int row = row0 + ((i < 4) ? (ty * 4 + i) : (64 + ty * 4 + i - 4));
        float o[8];
#pragma unroll
        for (int j = 0; j < 8; j++) {
            float xv = acc[i][j] + bj[j];
            float t = __builtin_amdgcn_exp2f(-fabsf(xv) * LOG2E);
            o[j] = fmaxf(xv, 0.f) + LN2 * __log2f(1.f + t);
        }
        unsigned short* op = (unsigned short*)dt + (size_t)row * D_IN + col0 + tx * 4;
        ushort4 p0, p1;
        p0.x = f2bf(o[0]); p0.y = f2bf(o[1]); p0.z = f2bf(o[2]); p0.w = f2bf(o[3]);
        p1.x = f2bf(o[4]); p1.y = f2bf(o[5]); p1.z = f2bf(o[6]); p1.w = f2bf(o[7]);
        *(ushort4*)&op[0]  = p0;
        *(ushort4*)&op[64] = p1;
    }
}

// ---------------------------------------------------------------------------
// Scan pass 1: per (b, chunk, d): local scan from h=0 over LC steps.
// ---------------------------------------------------------------------------
__global__ __launch_bounds__(256) void scan_pass1(const float* __restrict__ u,
                                                  const __hip_bfloat16* __restrict__ dt,
                                                  const float* __restrict__ xdbl,
                                                  const float* __restrict__ Alog,
                                                  float* __restrict__ Ssum,
                                                  float* __restrict__ q) {
    const int blk = blockIdx.x;
    const int b  = blk >> 9;
    const int c  = (blk >> 3) & 63;
    const int db = blk & 7;
    const int tid = threadIdx.x;
    const int d = db * 256 + tid;
    const int t0 = c * LC;

    float A2[16];
#pragma unroll
    for (int n4 = 0; n4 < 4; n4++) {
        float4 a = *(const float4*)&Alog[(size_t)d * 16 + n4 * 4];
        A2[n4 * 4 + 0] = -expf(a.x) * LOG2E;
        A2[n4 * 4 + 1] = -expf(a.y) * LOG2E;
        A2[n4 * 4 + 2] = -expf(a.z) * LOG2E;
        A2[n4 * 4 + 3] = -expf(a.w) * LOG2E;
    }

    float h[16];
#pragma unroll
    for (int n = 0; n < 16; n++) h[n] = 0.f;
    float S = 0.f;

    const float* bcrow = &xdbl[(size_t)(b * LL + t0) * 96];   // uniform
    const __hip_bfloat16* dtp = &dt[(size_t)(b * LL + t0) * D_IN + d];
    const float* up  = &u[(size_t)(b * LL + t0) * D_IN + d];
    float dt_nxt = __bfloat162float(dtp[0]), u_nxt = up[0];
    for (int t = 0; t < LC; t++) {
        float dv = dt_nxt, uv = u_nxt;
        if (t + 1 < LC) {
            dt_nxt = __bfloat162float(dtp[(size_t)(t + 1) * D_IN]);
            u_nxt  = up[(size_t)(t + 1) * D_IN];
        }
        S += dv;
        float dtu = dv * uv;
        float4 b0 = *(const float4*)&bcrow[t * 96 + 64];
        float4 b1 = *(const float4*)&bcrow[t * 96 + 68];
        float4 b2 = *(const float4*)&bcrow[t * 96 + 72];
        float4 b3 = *(const float4*)&bcrow[t * 96 + 76];
        const float Bt[16] = {b0.x,b0.y,b0.z,b0.w, b1.x,b1.y,b1.z,b1.w,
                              b2.x,b2.y,b2.z,b2.w, b3.x,b3.y,b3.z,b3.w};
#pragma unroll
        for (int n = 0; n < 16; n++) {
            float a = __builtin_amdgcn_exp2f(dv * A2[n]);
            h[n] = fmaf(a, h[n], dtu * Bt[n]);
        }
    }
    Ssum[(size_t)(b * NCHUNK + c) * D_IN + d] = S;
#pragma unroll
    for (int n = 0; n < 16; n++)
        q[((size_t)((b * NCHUNK + c) * 16 + n)) * D_IN + d] = h[n];
}

// ---------------------------------------------------------------------------
// Combine: per (b,n,d): sequentially fold chunks IN-PLACE (pipelined loads).
// On exit q[b][c][n][d] holds h_init for chunk c.
// ---------------------------------------------------------------------------
__global__ __launch_bounds__(256) void scan_combine(const float* __restrict__ Alog,
                                                    const float* __restrict__ Ssum,
                                                    float* __restrict__ q) {
    const int gid = blockIdx.x * 256 + threadIdx.x;  // B*16*2048 = 65536
    const int d = gid & 2047;
    const int n = (gid >> 11) & 15;
    const int b = gid >> 15;
    const float A2 = -expf(Alog[(size_t)d * 16 + n]) * LOG2E;
    const size_t qstride = (size_t)16 * D_IN;
    size_t idx = ((size_t)((b * NCHUNK) * 16 + n)) * D_IN + d;
    const float* sp = &Ssum[(size_t)(b * NCHUNK) * D_IN + d];
    float h = 0.f;
    float qv = q[idx];
    float S  = sp[0];
    for (int c = 0; c < NCHUNK; c++) {
        float qn = 0.f, Sn = 0.f;
        if (c + 1 < NCHUNK) {              // prefetch next before the chain
            qn = q[idx + qstride];
            Sn = sp[(size_t)(c + 1) * D_IN];
        }
        q[idx] = h;                        // h_init for chunk c
        h = fmaf(__builtin_amdgcn_exp2f(A2 * S), h, qv);
        qv = qn; S = Sn; idx += qstride;
    }
}

// ---------------------------------------------------------------------------
// Scan pass 2: re-scan each chunk from h_init, emit y = sum_n h*C + u*D (fp32)
// ---------------------------------------------------------------------------
__global__ __launch_bounds__(256) void scan_pass2(const float* __restrict__ u,
                                                  const __hip_bfloat16* __restrict__ dt,
                                                  const float* __restrict__ xdbl,
                                                  const float* __restrict__ Alog,
                                                  const float* __restrict__ Dv,
                                                  const float* __restrict__ hinit,
                                                  float* __restrict__ out) {
    const int blk = blockIdx.x;
    const int b  = blk >> 9;
    const int c  = (blk >> 3) & 63;
    const int db = blk & 7;
    const int tid = threadIdx.x;
    const int d = db * 256 + tid;
    const int t0 = c * LC;

    float A2[16];
#pragma unroll
    for (int n4 = 0; n4 < 4; n4++) {
        float4 a = *(const float4*)&Alog[(size_t)d * 16 + n4 * 4];
        A2[n4 * 4 + 0] = -expf(a.x) * LOG2E;
        A2[n4 * 4 + 1] = -expf(a.y) * LOG2E;
        A2[n4 * 4 + 2] = -expf(a.z) * LOG2E;
        A2[n4 * 4 + 3] = -expf(a.w) * LOG2E;
    }
    const float Dd = Dv[d];
    float h[16];
#pragma unroll
    for (int n = 0; n < 16; n++)
        h[n] = hinit[((size_t)((b * NCHUNK + c) * 16 + n)) * D_IN + d];

    const float* bcrow = &xdbl[(size_t)(b * LL + t0) * 96];   // uniform
    const __hip_bfloat16* dtp = &dt[(size_t)(b * LL + t0) * D_IN + d];
    const float* up  = &u[(size_t)(b * LL + t0) * D_IN + d];
    float* op = &out[(size_t)(b * LL + t0) * D_IN + d];
    float dt_nxt = __bfloat162float(dtp[0]), u_nxt = up[0];
    for (int t = 0; t < LC; t++) {
        float dv = dt_nxt, uv = u_nxt;
        if (t + 1 < LC) {
            dt_nxt = __bfloat162float(dtp[(size_t)(t + 1) * D_IN]);
            u_nxt  = up[(size_t)(t + 1) * D_IN];
        }
        float dtu = dv * uv;
        float4 b0 = *(const float4*)&bcrow[t * 96 + 64];
        float4 b1 = *(const float4*)&bcrow[t * 96 + 68];
        float4 b2 = *(const float4*)&bcrow[t * 96 + 72];
        float4 b3 = *(const float4*)&bcrow[t * 96 + 76];
        float4 c0v = *(const float4*)&bcrow[t * 96 + 80];
        float4 c1v = *(const float4*)&bcrow[t * 96 + 84];
        float4 c2v = *(const float4*)&bcrow[t * 96 + 88];
        float4 c3v = *(const float4*)&bcrow[t * 96 + 92];
        const float Bt[16] = {b0.x,b0.y,b0.z,b0.w, b1.x,b1.y,b1.z,b1.w,
                              b2.x,b2.y,b2.z,b2.w, b3.x,b3.y,b3.z,b3.w};
        const float Ct[16] = {c0v.x,c0v.y,c0v.z,c0v.w, c1v.x,c1v.y,c1v.z,c1v.w,
                              c2v.x,c2v.y,c2v.z,c2v.w, c3v.x,c3v.y,c3v.z,c3v.w};
        float y = 0.f;
#pragma unroll
        for (int n = 0; n < 16; n++) {
            float a = __builtin_amdgcn_exp2f(dv * A2[n]);
            h[n] = fmaf(a, h[n], dtu * Bt[n]);
            y = fmaf(h[n], Ct[n], y);
        }
        op[(size_t)t * D_IN] = fmaf(uv, Dd, y);
    }
}

// ---------------------------------------------------------------------------
extern "C" void kernel_launch(void* const* d_in, const int* in_sizes, int n_in,
                              void* d_out, int out_size, void* d_ws, size_t ws_size,
                              hipStream_t stream) {
    const float* u    = (const float*)d_in[0];
    const float* Alog = (const float*)d_in[1];
    const float* Dv   = (const float*)d_in[2];
    const float* Wx   = (const float*)d_in[3];
    const float* Wdt  = (const float*)d_in[4];
    const float* bdt  = (const float*)d_in[5];
    float* out = (float*)d_out;

    float* ws   = (float*)d_ws;
    float* xdbl = ws;                                   // 393216 f
    // dtb (bf16) occupies 8388608 ushort = 4194304 f; Ssum 262144 f; q 4194304 f.
    __hip_bfloat16* dtb = (__hip_bfloat16*)(ws + 393216);
    float* Ssum = ws + 393216 + 4194304;
    float* q    = Ssum + (size_t)BB * NCHUNK * D_IN;
    // split-K partials: 16 * 393216 = 6291456 f, alias dtb+Ssum+q (8650752 f),
    // all of which are written only AFTER reduce_xdbl consumes the partials.
    float* part = ws + 393216;
    // total ws use: 393216 + 8650752 floats = 34.5 MB

    gemm_xdbl <<<32 * X1_KSPLIT, 256, 0, stream>>>(u, Wx, part);
    reduce_xdbl<<<384,           256, 0, stream>>>(part, xdbl);
    gemm_dt   <<<32 * 16,        256, 0, stream>>>(xdbl, Wdt, bdt, dtb);
    scan_pass1<<<BB * NCHUNK * 8, 256, 0, stream>>>(u, dtb, xdbl, Alog, Ssum, q);
    scan_combine<<<BB * 16 * D_IN / 256, 256, 0, stream>>>(Alog, Ssum, q);
    scan_pass2<<<BB * NCHUNK * 8, 256, 0, stream>>>(u, dtb, xdbl, Alog, Dv, q, out);
}